// Round 1
// baseline (97.896 us; speedup 1.0000x reference)
//
#include <hip/hip_runtime.h>
#include <math.h>

#define F      32
#define BATCH  2048
#define K      64
#define H      64
#define NPAIR  496     // 32*31/2
#define NTROW  31      // 496/16 pair-tile rows
#define EPB    2       // batch elems per block (2 waves per elem)
#define NBLK   (BATCH / EPB)   // 1024 blocks -> 4 blocks/CU -> 4 waves/SIMD

typedef float    v4f __attribute__((ext_vector_type(4)));
typedef _Float16 v8h __attribute__((ext_vector_type(8)));
typedef __fp16   h2  __attribute__((ext_vector_type(2)));   // cvt_pkrtz return type

union V8H { v8h v; h2 h[4]; };

// ---------------------------------------------------------------------------
// Block = 4 waves = 2 batch elems; waves (2e, 2e+1) share elem b0+e and split
// the 31 pair-tile rows 16/15. Doubles resident waves/SIMD (2 -> 4) vs the
// EPB=4 version to hide gather + at_w-load latency; per-wave serial loop
// halves. Partial sums combined through LDS.
// ---------------------------------------------------------------------------
__global__ __launch_bounds__(256, 4)
void afm_fwd(const int*   __restrict__ x,      // [F,B]
             const float* __restrict__ emb_v,  // [VOCAB,K]
             const float* __restrict__ at_w,   // [K,H]
             const float* __restrict__ at_b,   // [H]
             const float* __restrict__ at_h,   // [H,1]
             const float* __restrict__ p,      // [K,1]
             const float* __restrict__ w0,     // [1]
             const float* __restrict__ w1,     // [VOCAB,1]
             float*       __restrict__ out)    // [B]
{
    __shared__ __align__(16) _Float16 Vsh[EPB][F][72];   // 9.2 KB, 144B rows
    __shared__ unsigned short pairs_sh[NPAIR + 16];
    __shared__ float fm_sh[EPB * F];
    __shared__ float red_sh[4];

    const int t    = threadIdx.x;
    const int lane = t & 63;
    const int wv   = t >> 6;
    const int c    = lane & 15;
    const int quad = lane >> 4;
    const int b0   = blockIdx.x * EPB;

    // ---- pair table: closed-form unrank of triu index, 2 entries/thread ----
    if (t < NPAIR / 2) {
        #pragma unroll
        for (int u2 = 0; u2 < 2; ++u2) {
            int pr = t * 2 + u2;
            int r  = NPAIR - 1 - pr;
            int u  = (int)((sqrtf((float)(8 * r + 1)) - 1.0f) * 0.5f);
            if (u * (u + 1) / 2 > r) --u;                 // fp guard
            if ((u + 1) * (u + 2) / 2 <= r) ++u;
            int i   = F - 2 - u;
            int off = r - u * (u + 1) / 2;
            int j   = F - 1 - off;
            pairs_sh[pr] = (unsigned short)(i | (j << 8));
        }
    }

    // ---- gather V rows for 2 elems, fp32 -> f16 into LDS (4 thr/row) ----
    {
        int row  = t >> 2;             // 0..63
        int elem = row >> 5, f = row & 31, qtr = t & 3;
        int idx  = x[f * BATCH + b0 + elem];
        const float4* src = (const float4*)&emb_v[idx * K + qtr * 16];
        #pragma unroll
        for (int j4 = 0; j4 < 2; ++j4) {
            float4 a = src[j4 * 2], b = src[j4 * 2 + 1];
            V8H w;
            w.h[0] = __builtin_amdgcn_cvt_pkrtz(a.x, a.y);
            w.h[1] = __builtin_amdgcn_cvt_pkrtz(a.z, a.w);
            w.h[2] = __builtin_amdgcn_cvt_pkrtz(b.x, b.y);
            w.h[3] = __builtin_amdgcn_cvt_pkrtz(b.z, b.w);
            *(v8h*)&Vsh[elem][f][qtr * 16 + j4 * 8] = w.v;
        }
    }
    if (t < EPB * F) {
        int elem = t >> 5, f = t & 31;
        fm_sh[t] = w1[x[f * BATCH + b0 + elem]];
    }

    // ---- B fragments built directly from at_w (+ p as 5th N-tile) ----
    v8h bf[5][2];
    #pragma unroll
    for (int kk = 0; kk < 2; ++kk) {
        #pragma unroll
        for (int nt = 0; nt < 4; ++nt) {
            V8H w;
            #pragma unroll
            for (int e = 0; e < 8; e += 2) {
                int k = kk * 32 + quad * 8 + e;
                w.h[e >> 1] = __builtin_amdgcn_cvt_pkrtz(
                    at_w[k * H + nt * 16 + c], at_w[(k + 1) * H + nt * 16 + c]);
            }
            bf[nt][kk] = w.v;
        }
        float4 p0 = *(const float4*)&p[kk * 32 + quad * 8];
        float4 p1 = *(const float4*)&p[kk * 32 + quad * 8 + 4];
        V8H w;
        w.h[0] = __builtin_amdgcn_cvt_pkrtz(p0.x, p0.y);
        w.h[1] = __builtin_amdgcn_cvt_pkrtz(p0.z, p0.w);
        w.h[2] = __builtin_amdgcn_cvt_pkrtz(p1.x, p1.y);
        w.h[3] = __builtin_amdgcn_cvt_pkrtz(p1.z, p1.w);
        bf[4][kk] = w.v;
    }

    float ah[4];
    v4f abv[5];
    #pragma unroll
    for (int nt = 0; nt < 4; ++nt) {
        float abn = at_b[nt * 16 + c];
        ah[nt]  = at_h[nt * 16 + c];
        abv[nt] = (v4f){abn, abn, abn, abn};   // bias as MFMA C operand
    }
    abv[4] = (v4f){0.f, 0.f, 0.f, 0.f};

    __syncthreads();

    // ---- main loop: wave wv -> elem wv>>1, tile-rows [half*16, half?31:16) --
    const int elem  = wv >> 1;
    const int half  = wv & 1;
    const int trBeg = half * 16;
    const int trEnd = half ? NTROW : 16;
    const _Float16* Vw = &Vsh[elem][0][0];
    float accTot = 0.f;

    unsigned short pk = pairs_sh[trBeg * 16 + c];
    int pi = pk & 255, pj = pk >> 8;
    v8h vi0 = *(const v8h*)&Vw[pi * 72 + quad * 8];
    v8h vj0 = *(const v8h*)&Vw[pj * 72 + quad * 8];
    v8h vi1 = *(const v8h*)&Vw[pi * 72 + 32 + quad * 8];
    v8h vj1 = *(const v8h*)&Vw[pj * 72 + 32 + quad * 8];

    for (int tr = trBeg; tr < trEnd; ++tr) {
        v8h af0 = vi0 * vj0;                   // v_pk_mul_f16
        v8h af1 = vi1 * vj1;

        if (tr + 1 < trEnd) {                  // rolling 1-deep prefetch
            pk = pairs_sh[(tr + 1) * 16 + c];
            pi = pk & 255; pj = pk >> 8;
            vi0 = *(const v8h*)&Vw[pi * 72 + quad * 8];
            vj0 = *(const v8h*)&Vw[pj * 72 + quad * 8];
            vi1 = *(const v8h*)&Vw[pi * 72 + 32 + quad * 8];
            vj1 = *(const v8h*)&Vw[pj * 72 + 32 + quad * 8];
        }

        v4f acc[5];
        #pragma unroll
        for (int nt = 0; nt < 5; ++nt) {
            v4f a = __builtin_amdgcn_mfma_f32_16x16x32_f16(af0, bf[nt][0], abv[nt], 0, 0, 0);
            acc[nt] = __builtin_amdgcn_mfma_f32_16x16x32_f16(af1, bf[nt][1], a, 0, 0, 0);
        }

        #pragma unroll
        for (int r = 0; r < 4; ++r) {
            float sp = 0.f;
            #pragma unroll
            for (int nt = 0; nt < 4; ++nt)
                sp = fmaf(fmaxf(acc[nt][r], 0.f), ah[nt], sp);
            accTot = fmaf(acc[4][r], sp, accTot);   // acc[4][r] = q[m]
        }
    }

    // ---- fold fm1 partials once per elem (half 0 only), reduce per wave ----
    if (half == 0)
        accTot += (lane < F) ? fm_sh[elem * F + lane] : 0.f;
    accTot += __shfl_xor(accTot, 1);
    accTot += __shfl_xor(accTot, 2);
    accTot += __shfl_xor(accTot, 4);
    accTot += __shfl_xor(accTot, 8);
    accTot += __shfl_xor(accTot, 16);
    accTot += __shfl_xor(accTot, 32);
    if (lane == 0) red_sh[wv] = accTot;
    __syncthreads();

    // ---- combine the two half-waves of each elem, sigmoid, store ----
    if (t < EPB) {
        float logit = red_sh[2 * t] + red_sh[2 * t + 1] + w0[0];
        out[b0 + t] = 1.f / (1.f + expf(-logit));
    }
}

extern "C" void kernel_launch(void* const* d_in, const int* in_sizes, int n_in,
                              void* d_out, int out_size, void* d_ws, size_t ws_size,
                              hipStream_t stream) {
    const int*   x     = (const int*)  d_in[0];
    const float* emb_v = (const float*)d_in[1];
    const float* at_w  = (const float*)d_in[2];
    const float* at_b  = (const float*)d_in[3];
    const float* at_h  = (const float*)d_in[4];
    const float* p     = (const float*)d_in[5];
    const float* w0    = (const float*)d_in[6];
    const float* w1    = (const float*)d_in[7];
    float* out = (float*)d_out;

    afm_fwd<<<NBLK, 256, 0, stream>>>(x, emb_v, at_w, at_b, at_h, p, w0, w1, out);
}